// Round 2
// baseline (37183.472 us; speedup 1.0000x reference)
//
#include <hip/hip_runtime.h>
#include <hip/hip_bf16.h>
#include <stdint.h>

typedef __bf16 bf16;
typedef __bf16 bf16x8 __attribute__((ext_vector_type(8)));
typedef __bf16 bf16x4 __attribute__((ext_vector_type(4)));
typedef float f32x16 __attribute__((ext_vector_type(16)));
typedef float f32x2 __attribute__((ext_vector_type(2)));

#define LL 1024
#define BB 64
#define HH 512
#define NAWG 12
#define NBWG 4

// ---------------- ws layout (bytes) ----------------
#define OFF_X      ((size_t)0)           // [LL][BB][HH] bf16   67,108,864
#define OFF_WGSEL  ((size_t)67108864)    // [1536][512] bf16     1,572,864
#define OFF_WCIH   ((size_t)68681728)    // [512][512]  bf16       524,288
#define OFF_A2     ((size_t)69206016)    // [64][512] bf16          65,536
#define OFF_ZP     ((size_t)69271552)    // [64][512][2] f32       262,144
#define OFF_CTR    ((size_t)69533696)    // 512 B counters

static __device__ __forceinline__ float sigm(float x) {
  return 1.0f / (1.0f + __expf(-x));
}
static __device__ __forceinline__ float tanhx(float x) {
  x = fminf(15.0f, fmaxf(-15.0f, x));
  float e = __expf(2.0f * x);
  return (e - 1.0f) / (e + 1.0f);
}

// ---- coherent (cross-XCD, MALL-level) access helpers: no cache-wide fences ----
static __device__ __forceinline__ void st_coh_f32(float* p, float v) {
  asm volatile("global_store_dword %0, %1, off sc0 sc1" :: "v"(p), "v"(v) : "memory");
}
static __device__ __forceinline__ void st_coh_bf16(bf16* p, bf16 v) {
  unsigned u = (unsigned)__builtin_bit_cast(unsigned short, v);
  asm volatile("global_store_short %0, %1, off sc0 sc1" :: "v"(p), "v"(u) : "memory");
}
static __device__ __forceinline__ void ld_coh_b128(const bf16* p, bf16x8& d) {
  asm volatile("global_load_dwordx4 %0, %1, off sc0 sc1" : "=v"(d) : "v"(p) : "memory");
}
static __device__ __forceinline__ void ld_coh_b64(const float* p, f32x2& d) {
  asm volatile("global_load_dwordx2 %0, %1, off sc0 sc1" : "=v"(d) : "v"(p) : "memory");
}

// acquire: relaxed poll (agent-scope atomic load is coherent by construction).
// No cache invalidate: bypass loads read MALL; cached reads are first-touch rings.
static __device__ __forceinline__ void wgwait(unsigned* c, unsigned tgt) {
  if (threadIdx.x == 0) {
    while (__hip_atomic_load(c, __ATOMIC_RELAXED, __HIP_MEMORY_SCOPE_AGENT) < tgt) {}
  }
  __syncthreads();
}
// release: all data stores were write-through (sc0 sc1); drain them, then
// release-atomic (wbl2 on a ~clean L2 is cheap since we never dirty L2).
static __device__ __forceinline__ void wgsignal(unsigned* c) {
  asm volatile("s_waitcnt vmcnt(0)" ::: "memory");
  __syncthreads();
  if (threadIdx.x == 0) {
    __hip_atomic_fetch_add(c, 1u, __ATOMIC_RELEASE, __HIP_MEMORY_SCOPE_AGENT);
  }
}

// swizzled LDS b-frag read: row i (weight out-col), 8 consecutive k; byte ^= (i&7)<<4
static __device__ __forceinline__ bf16x8 ldsfrag(const bf16* w, int i, int k) {
  unsigned byte = ((unsigned)i << 10) + ((unsigned)k << 1);
  byte ^= ((unsigned)(i & 7) << 4);
  return *(const bf16x8*)((const char*)w + byte);
}

__global__ __launch_bounds__(256) void k_cvt_x(const float* __restrict__ in,
                                               bf16* __restrict__ o) {
  size_t i = ((size_t)blockIdx.x * 256 + threadIdx.x) * 4;
  float4 f = *(const float4*)(in + i);
  bf16x4 v;
  v[0] = (bf16)f.x; v[1] = (bf16)f.y; v[2] = (bf16)f.z; v[3] = (bf16)f.w;
  *(bf16x4*)(o + i) = v;
}

// pack W_gih rows {rl:0..511, zl:1024..1535, z:2048..2559} -> wgsel[1536][512] bf16,
// and W_cih -> wcb[512][512] bf16
__global__ __launch_bounds__(256) void k_cvt_w(const float* __restrict__ wgih,
                                               const float* __restrict__ wcf,
                                               bf16* __restrict__ wgsel,
                                               bf16* __restrict__ wcb) {
  int i = blockIdx.x * 256 + threadIdx.x;
  const int NQ1 = (1536 * 512) / 4;
  const float* s;
  bf16* d;
  if (i < NQ1) {
    int e = i * 4;
    int p = e >> 9, k = e & 511;
    int shift = (p < 512) ? 0 : ((p < 1024) ? 512 : 1024);
    s = wgih + (size_t)(p + shift) * 512 + k;
    d = wgsel + (size_t)p * 512 + k;
  } else {
    int e = (i - NQ1) * 4;
    int n = e >> 9, k = e & 511;
    s = wcf + (size_t)n * 512 + k;
    d = wcb + (size_t)n * 512 + k;
  }
  float4 f = *(const float4*)s;
  bf16x4 v;
  v[0] = (bf16)f.x; v[1] = (bf16)f.y; v[2] = (bf16)f.z; v[3] = (bf16)f.w;
  *(bf16x4*)d = v;
}

// Persistent recurrence kernel: 16 WGs x 512 thr (8 waves = 2 row-tiles x 4 col-tiles).
// WGs 0-3: rl (gate cols 0-511), 4-7: zl, 8-11: z, 12-15: cell (hidden cols).
__global__ __launch_bounds__(512) void k_main(
    const bf16* __restrict__ xbf, const bf16* __restrict__ wgsel,
    const bf16* __restrict__ wcb, const float* __restrict__ wglhh,
    const float* __restrict__ wclhh, const float* __restrict__ bg,
    const float* __restrict__ bc, float* __restrict__ out,
    bf16* __restrict__ a2, float* __restrict__ zp, unsigned* __restrict__ ctrs) {
  __shared__ bf16 wlds[128 * 512];  // 128 KB recurrent-weight slice (swizzled)
  const int wg = blockIdx.x;
  const int tid = threadIdx.x;
  const int lane = tid & 63;
  const int wave = tid >> 6;
  unsigned* b_done = ctrs;        // +4 per step (h published)
  unsigned* c_rl = ctrs + 32;     // +4 per step (a2 published)   [128B apart]
  unsigned* c_z = ctrs + 64;      // +8 per step (zl,z published)
  const bool isA = (wg < NAWG);
  const int gsel = isA ? (wg >> 2) : 0;   // 0 rl, 1 zl, 2 z

  // ---- stage this WG's recurrent weights into LDS (fp32 -> bf16, swizzled) ----
  {
    const float* wsrc;
    if (isA) {
      int base = (gsel == 0 ? 0 : (gsel == 1 ? 1024 : 2048)) + (wg & 3) * 128;
      wsrc = wglhh + (size_t)base * HH;
    } else {
      wsrc = wclhh + (size_t)((wg - NAWG) * 128) * HH;
    }
    for (int u = tid; u < 128 * 64; u += 512) {
      int i = u >> 6, k8 = (u & 63) << 3;
      const float* s = wsrc + (size_t)i * HH + k8;
      bf16x8 v;
      #pragma unroll
      for (int j = 0; j < 8; ++j) v[j] = (bf16)s[j];
      unsigned byte = ((unsigned)i << 10) + ((unsigned)k8 << 1);
      byte ^= ((unsigned)(i & 7) << 4);
      *(bf16x8*)((char*)wlds + byte) = v;
    }
    __syncthreads();
  }

  const int m0 = (wave & 1) * 32;         // row tile (batch)
  const int ct = wave >> 1;               // col sub-tile 0..3
  const int kq = (lane >> 5) * 8;         // k-half offset within K=16 step
  const int lr = lane & 31;
  const int mrow = m0 + 4 * (lane >> 5);  // C-layout row base

  if (isA) {
    const int p = wg * 128 + ct * 32 + lr;  // packed gate col 0..1535
    const int shift = gsel * 512;
    const float bias = bg[p + shift];
    const int n = p - shift;                // unpacked col 0..511 (zl/z)

    auto xgemm = [&](int tt, f32x16& a_) {
      #pragma unroll
      for (int r = 0; r < 16; ++r) a_[r] = bias;
      const bf16* xa = xbf + (size_t)tt * (BB * HH);
      #pragma unroll 4
      for (int kk = 0; kk < 32; ++kk) {
        bf16x8 av = *(const bf16x8*)(xa + (size_t)(m0 + lr) * HH + kk * 16 + kq);
        bf16x8 bv = *(const bf16x8*)(wgsel + (size_t)p * HH + kk * 16 + kq);
        a_ = __builtin_amdgcn_mfma_f32_32x32x16_bf16(av, bv, a_, 0, 0, 0);
      }
    };

    f32x16 acc;
    xgemm(0, acc);
    for (int t = 0; t < LL; ++t) {
      if (t > 0) {
        wgwait(b_done, 4u * (unsigned)t);  // h(t-1) ready
        // a-frags from fp32 h in out[] (cached: first-touch ring, writer wrote-through)
        const float* hrow = out + (size_t)(m0 + lr) * (LL * HH) + (size_t)(t - 1) * HH + kq;
        #pragma unroll 4
        for (int kk = 0; kk < 32; ++kk) {
          float4 f0 = *(const float4*)(hrow + kk * 16);
          float4 f1 = *(const float4*)(hrow + kk * 16 + 4);
          bf16x8 av;
          av[0] = (bf16)f0.x; av[1] = (bf16)f0.y; av[2] = (bf16)f0.z; av[3] = (bf16)f0.w;
          av[4] = (bf16)f1.x; av[5] = (bf16)f1.y; av[6] = (bf16)f1.z; av[7] = (bf16)f1.w;
          bf16x8 bv = ldsfrag(wlds, ct * 32 + lr, kk * 16 + kq);
          acc = __builtin_amdgcn_mfma_f32_32x32x16_bf16(av, bv, acc, 0, 0, 0);
        }
      }
      if (gsel == 0) {
        #pragma unroll
        for (int r = 0; r < 16; ++r) {
          int m = mrow + (r & 3) + 8 * (r >> 2);
          float g = sigm(acc[r]);
          float hp = (t > 0) ? out[(size_t)m * (LL * HH) + (size_t)(t - 1) * HH + p] : 0.0f;
          st_coh_bf16(a2 + (size_t)m * HH + p, (bf16)(g * hp));
        }
        wgsignal(c_rl);
      } else {
        #pragma unroll
        for (int r = 0; r < 16; ++r) {
          int m = mrow + (r & 3) + 8 * (r >> 2);
          st_coh_f32(zp + ((size_t)m * HH + n) * 2 + (gsel - 1), sigm(acc[r]));
        }
        wgsignal(c_z);
      }
      if (t + 1 < LL) xgemm(t + 1, acc);  // shadow compute
    }
  } else {
    const int n2 = (wg - NAWG) * 128 + ct * 32 + lr;  // hidden col
    const float bias = bc[n2];

    auto xcgemm = [&](int tt, f32x16& a_) {
      #pragma unroll
      for (int r = 0; r < 16; ++r) a_[r] = bias;
      const bf16* xa = xbf + (size_t)tt * (BB * HH);
      #pragma unroll 4
      for (int kk = 0; kk < 32; ++kk) {
        bf16x8 av = *(const bf16x8*)(xa + (size_t)(m0 + lr) * HH + kk * 16 + kq);
        bf16x8 bv = *(const bf16x8*)(wcb + (size_t)n2 * HH + kk * 16 + kq);
        a_ = __builtin_amdgcn_mfma_f32_32x32x16_bf16(av, bv, a_, 0, 0, 0);
      }
    };

    f32x16 acc;
    xcgemm(0, acc);
    float hreg[16];
    #pragma unroll
    for (int r = 0; r < 16; ++r) hreg[r] = 0.0f;

    for (int t = 0; t < LL; ++t) {
      wgwait(c_rl, 4u * (unsigned)(t + 1));  // a2(t) ready
      {
        const bf16* abase = a2 + (size_t)(m0 + lr) * HH + kq;
        bf16x8 af0[8], af1[8];
        #pragma unroll
        for (int j = 0; j < 8; ++j) ld_coh_b128(abase + j * 16, af0[j]);
        #pragma unroll
        for (int b4 = 0; b4 < 4; ++b4) {
          bf16x8* cur = (b4 & 1) ? af1 : af0;
          bf16x8* nxt = (b4 & 1) ? af0 : af1;
          if (b4 < 3) {
            #pragma unroll
            for (int j = 0; j < 8; ++j)
              ld_coh_b128(abase + ((b4 + 1) * 8 + j) * 16, nxt[j]);
            asm volatile("s_waitcnt vmcnt(8)" ::: "memory");
          } else {
            asm volatile("s_waitcnt vmcnt(0)" ::: "memory");
          }
          __builtin_amdgcn_sched_barrier(0);
          #pragma unroll
          for (int j = 0; j < 8; ++j) {
            bf16x8 bv = ldsfrag(wlds, ct * 32 + lr, (b4 * 8 + j) * 16 + kq);
            acc = __builtin_amdgcn_mfma_f32_32x32x16_bf16(cur[j], bv, acc, 0, 0, 0);
          }
        }
      }
      wgwait(c_z, 8u * (unsigned)(t + 1));  // zl,z(t) ready
      f32x2 zv[16];
      #pragma unroll
      for (int r = 0; r < 16; ++r) {
        int m = mrow + (r & 3) + 8 * (r >> 2);
        ld_coh_b64(zp + ((size_t)m * HH + n2) * 2, zv[r]);
      }
      asm volatile("s_waitcnt vmcnt(0)" ::: "memory");
      __builtin_amdgcn_sched_barrier(0);
      #pragma unroll
      for (int r = 0; r < 16; ++r) {
        int m = mrow + (r & 3) + 8 * (r >> 2);
        float cell = tanhx(acc[r]);
        float h = zv[r][0] * hreg[r] + zv[r][1] * cell;  // zl*h_prev + z*cell
        hreg[r] = h;                                     // h_prev lives in registers
        st_coh_f32(out + (size_t)m * (LL * HH) + (size_t)t * HH + n2, h);
      }
      wgsignal(b_done);
      if (t + 1 < LL) xcgemm(t + 1, acc);  // shadow compute
    }
  }
}

extern "C" void kernel_launch(void* const* d_in, const int* in_sizes, int n_in,
                              void* d_out, int out_size, void* d_ws, size_t ws_size,
                              hipStream_t stream) {
  (void)in_sizes; (void)n_in; (void)out_size; (void)ws_size;
  const float* x     = (const float*)d_in[0];
  // d_in[1] = indexes (chain tree, unused)
  const float* wgih  = (const float*)d_in[2];
  const float* bg    = (const float*)d_in[3];
  const float* wglhh = (const float*)d_in[4];
  // d_in[5] = W_grhh unused (right child == 0)
  const float* wcihf = (const float*)d_in[6];
  const float* bc    = (const float*)d_in[7];
  const float* wclhh = (const float*)d_in[8];
  // d_in[9] = W_crhh unused
  float* out = (float*)d_out;

  char* ws = (char*)d_ws;
  bf16* xbf     = (bf16*)(ws + OFF_X);
  bf16* wgsel   = (bf16*)(ws + OFF_WGSEL);
  bf16* wcb     = (bf16*)(ws + OFF_WCIH);
  bf16* a2      = (bf16*)(ws + OFF_A2);
  float* zp     = (float*)(ws + OFF_ZP);
  unsigned* ctr = (unsigned*)(ws + OFF_CTR);

  // counters must start at 0 every call (ws not re-poisoned between replays)
  hipMemsetAsync(ctr, 0, 512, stream);
  // output_t tail is zeros per reference
  hipMemsetAsync(out + (size_t)BB * LL * HH, 0, (size_t)BB * HH * sizeof(float), stream);

  k_cvt_x<<<dim3(32768), dim3(256), 0, stream>>>(x, xbf);
  k_cvt_w<<<dim3(1024), dim3(256), 0, stream>>>(wgih, wcihf, wgsel, wcb);
  k_main<<<dim3(NAWG + NBWG), dim3(512), 0, stream>>>(xbf, wgsel, wcb, wglhh, wclhh,
                                                      bg, bc, out, a2, zp, ctr);
}

// Round 3
// 22699.200 us; speedup vs baseline: 1.6381x; 1.6381x over previous
//
#include <hip/hip_runtime.h>
#include <hip/hip_bf16.h>
#include <stdint.h>

typedef __bf16 bf16;
typedef __bf16 bf16x8 __attribute__((ext_vector_type(8)));
typedef __bf16 bf16x4 __attribute__((ext_vector_type(4)));
typedef float f32x16 __attribute__((ext_vector_type(16)));

#define LL 1024
#define BB 64
#define HH 512
#define NR 8    // rl WGs, 64 gate-cols each
#define NC 16   // cell WGs, 32 hidden-cols each
#define MFMA32(a, b, c) __builtin_amdgcn_mfma_f32_32x32x16_bf16(a, b, c, 0, 0, 0)

// ---------------- ws layout (bytes) ----------------
#define OFF_X      ((size_t)0)           // [LL][BB][HH] bf16       67,108,864
#define OFF_WGSEL  ((size_t)67108864)    // [1536][512] bf16 (x-side rl,zl,z)
#define OFF_WCIH   ((size_t)68681728)    // [512][512]  bf16 (x-side cell)
#define OFF_WHHZZ  ((size_t)69206016)    // [1024][512] bf16 (h-side zl,z)
#define OFF_HBUF   ((size_t)70254592)    // [2][64][512] bf16
#define OFF_A2     ((size_t)70385664)    // [2][64][512] bf16
#define OFF_CTR    ((size_t)70516736)    // stamps: astamp[8] @0, hstamp[16] @64B

static __device__ __forceinline__ float sigm(float x) {
  return 1.0f / (1.0f + __expf(-x));
}
static __device__ __forceinline__ float tanhx(float x) {
  x = fminf(15.0f, fmaxf(-15.0f, x));
  float e = __expf(2.0f * x);
  return (e - 1.0f) / (e + 1.0f);
}

// ---- raw vmem helpers (manual vmcnt accounting; FIFO completion order) ----
static __device__ __forceinline__ unsigned ld_stamp(const unsigned* p) {
  unsigned s;
  asm volatile("global_load_dword %0, %1, off sc0 sc1\n\ts_waitcnt vmcnt(0)"
               : "=v"(s) : "v"(p) : "memory");
  return s;
}
static __device__ __forceinline__ void st_stamp(unsigned* p, unsigned v) {
  asm volatile("global_store_dword %0, %1, off sc0 sc1" :: "v"(p), "v"(v) : "memory");
}
static __device__ __forceinline__ void ld_frag(const bf16* p, bf16x8& d) {
  asm volatile("global_load_dwordx4 %0, %1, off sc0 sc1" : "=v"(d) : "v"(p) : "memory");
}
static __device__ __forceinline__ void ld_frag_c(const bf16* p, bf16x8& d) {  // cached
  asm volatile("global_load_dwordx4 %0, %1, off" : "=v"(d) : "v"(p) : "memory");
}
static __device__ __forceinline__ void ld_u16(const bf16* p, unsigned& d) {
  asm volatile("global_load_ushort %0, %1, off sc0 sc1" : "=v"(d) : "v"(p) : "memory");
}
static __device__ __forceinline__ void st_u16(bf16* p, unsigned v) {
  asm volatile("global_store_short %0, %1, off sc0 sc1" :: "v"(p), "v"(v) : "memory");
}
#define VWAIT(n) do { asm volatile("s_waitcnt vmcnt(" #n ")" ::: "memory"); \
                      __builtin_amdgcn_sched_barrier(0); } while (0)

// swizzled LDS b-frag read: row i, 8 consecutive k; byte ^= (i&7)<<4
static __device__ __forceinline__ bf16x8 ldsfrag(const bf16* w, int i, int k) {
  unsigned byte = ((unsigned)i << 10) + ((unsigned)k << 1);
  byte ^= ((unsigned)(i & 7) << 4);
  return *(const bf16x8*)((const char*)w + byte);
}

__global__ __launch_bounds__(256) void k_cvt_x(const float* __restrict__ in,
                                               bf16* __restrict__ o) {
  size_t i = ((size_t)blockIdx.x * 256 + threadIdx.x) * 4;
  float4 f = *(const float4*)(in + i);
  bf16x4 v;
  v[0] = (bf16)f.x; v[1] = (bf16)f.y; v[2] = (bf16)f.z; v[3] = (bf16)f.w;
  *(bf16x4*)(o + i) = v;
}

// wgsel: rows {rl:0..511 -> W_gih[0..511], zl:512..1023 -> W_gih[1024..1535],
//              z:1024..1535 -> W_gih[2048..2559]}
// wcb:   W_cih
// whhzz: rows {zl:0..511 -> W_glhh[1024..1535], z:512..1023 -> W_glhh[2048..2559]}
__global__ __launch_bounds__(256) void k_cvt_w(const float* __restrict__ wgih,
                                               const float* __restrict__ wcf,
                                               const float* __restrict__ wglhh,
                                               bf16* __restrict__ wgsel,
                                               bf16* __restrict__ wcb,
                                               bf16* __restrict__ whhzz) {
  int i = blockIdx.x * 256 + threadIdx.x;
  const int NQ1 = (1536 * 512) / 4;
  const int NQ2 = (512 * 512) / 4;
  const float* s;
  bf16* d;
  if (i < NQ1) {
    int e = i * 4;
    int p = e >> 9, k = e & 511;
    int src = (p < 512) ? p : ((p < 1024) ? (1024 + p - 512) : (2048 + p - 1024));
    s = wgih + (size_t)src * 512 + k;
    d = wgsel + (size_t)p * 512 + k;
  } else if (i < NQ1 + NQ2) {
    int e = (i - NQ1) * 4;
    int n = e >> 9, k = e & 511;
    s = wcf + (size_t)n * 512 + k;
    d = wcb + (size_t)n * 512 + k;
  } else {
    int e = (i - NQ1 - NQ2) * 4;
    int q = e >> 9, k = e & 511;
    int src = (q < 512) ? (1024 + q) : (2048 + q - 512);
    s = wglhh + (size_t)src * 512 + k;
    d = whhzz + (size_t)q * 512 + k;
  }
  float4 f = *(const float4*)s;
  bf16x4 v;
  v[0] = (bf16)f.x; v[1] = (bf16)f.y; v[2] = (bf16)f.z; v[3] = (bf16)f.w;
  *(bf16x4*)d = v;
}

// Persistent recurrence: 24 WGs x 256 thr.
// WGs 0..7  (R): rl gates, 64 cols each; 4 waves = 2 row-tiles x 2 col-tiles.
// WGs 8..23 (C): 32 hidden cols each; waves 0-1 cell, waves 2-3 zl/z.
__global__ __launch_bounds__(256) void k_main(
    const bf16* __restrict__ xbf, const bf16* __restrict__ wgsel,
    const bf16* __restrict__ wcb, const bf16* __restrict__ whhzz,
    const float* __restrict__ wglhh, const float* __restrict__ wclhh,
    const float* __restrict__ bg, const float* __restrict__ bc,
    float* __restrict__ out, bf16* __restrict__ hbuf,
    bf16* __restrict__ a2buf, unsigned* __restrict__ ctrs) {
  __shared__ __align__(16) char smem[64 * 1024];
  bf16* wlds = (bf16*)smem;                     // R: 64KB weights; C: 32KB
  float* zlzs = (float*)(smem + 32 * 1024);     // C: [2][64][32] f32 (16KB)

  const int wg = blockIdx.x, tid = threadIdx.x;
  const int lane = tid & 63, wave = tid >> 6;
  const int lr = lane & 31, kq = (lane >> 5) * 8;
  unsigned* astamp = ctrs;        // 8 u32 (one 32B line)
  unsigned* hstamp = ctrs + 16;   // 16 u32 (one 64B line)

  if (wg < NR) {
    // ================= R: rl gates =================
    const int m0 = 32 * (wave & 1);
    const int lc = 32 * (wave >> 1) + lr;   // local weight row 0..63
    const int p = wg * 64 + lc;             // rl col 0..511
    const int mrow = m0 + 4 * (lane >> 5);
    const float bias = bg[p];

    for (int u = tid; u < 64 * 64; u += 256) {
      int i = u >> 6, k8 = (u & 63) << 3;
      const float* s = wglhh + (size_t)(wg * 64 + i) * HH + k8;
      bf16x8 v;
      #pragma unroll
      for (int j = 0; j < 8; ++j) v[j] = (bf16)s[j];
      unsigned byte = ((unsigned)i << 10) + ((unsigned)k8 << 1);
      byte ^= ((unsigned)(i & 7) << 4);
      *(bf16x8*)((char*)wlds + byte) = v;
    }
    __syncthreads();

    auto xg = [&](int tt) {
      f32x16 a;
      #pragma unroll
      for (int r = 0; r < 16; ++r) a[r] = bias;
      const bf16* xa = xbf + (size_t)tt * (BB * HH) + (size_t)(m0 + lr) * HH + kq;
      const bf16* wb = wgsel + (size_t)p * HH + kq;
      #pragma unroll 4
      for (int kk = 0; kk < 32; ++kk) {
        bf16x8 av = *(const bf16x8*)(xa + kk * 16);
        bf16x8 bv = *(const bf16x8*)(wb + kk * 16);
        a = MFMA32(av, bv, a);
      }
      return a;
    };

    f32x16 accN = xg(1);                     // rl(0) unused: a2(0)==0
    for (int t = 1; t < LL; ++t) {
      f32x16 acc = accN;
      {  // poll h(t-1): stamps hold last-published-step+1
        const unsigned* sp = hstamp + (lane & 15);
        while (__any((int)(ld_stamp(sp) < (unsigned)t))) {}
      }
      __builtin_amdgcn_sched_barrier(0);
      const bf16* hs = hbuf + (size_t)((t - 1) & 1) * (BB * HH);
      const bf16* ha = hs + (size_t)(m0 + lr) * HH + kq;
      bf16x8 fA[8], fB[8];
      unsigned hv[16];
      // FIFO plan: fA(0-7) fB(8-15) | w8->fA | MFMA0 | fA(16-23) | w8->fB | MFMA1
      //            fB(24-31) u16x16 | w24->fA | MFMA2 | w16->fB | MFMA3 | w0->u
      #pragma unroll
      for (int j = 0; j < 8; ++j) ld_frag(ha + j * 16, fA[j]);
      #pragma unroll
      for (int j = 0; j < 8; ++j) ld_frag(ha + (8 + j) * 16, fB[j]);
      VWAIT(8);
      #pragma unroll
      for (int j = 0; j < 8; ++j) acc = MFMA32(fA[j], ldsfrag(wlds, lc, j * 16 + kq), acc);
      #pragma unroll
      for (int j = 0; j < 8; ++j) ld_frag(ha + (16 + j) * 16, fA[j]);
      VWAIT(8);
      #pragma unroll
      for (int j = 0; j < 8; ++j) acc = MFMA32(fB[j], ldsfrag(wlds, lc, (8 + j) * 16 + kq), acc);
      #pragma unroll
      for (int j = 0; j < 8; ++j) ld_frag(ha + (24 + j) * 16, fB[j]);
      #pragma unroll
      for (int r = 0; r < 16; ++r) {
        int m = mrow + (r & 3) + 8 * (r >> 2);
        ld_u16(hs + (size_t)m * HH + p, hv[r]);
      }
      VWAIT(24);
      #pragma unroll
      for (int j = 0; j < 8; ++j) acc = MFMA32(fA[j], ldsfrag(wlds, lc, (16 + j) * 16 + kq), acc);
      VWAIT(16);
      #pragma unroll
      for (int j = 0; j < 8; ++j) acc = MFMA32(fB[j], ldsfrag(wlds, lc, (24 + j) * 16 + kq), acc);
      VWAIT(0);
      // publish a2 = sigm(rl) * h_prev(bf16)
      bf16* ad = a2buf + (size_t)(t & 1) * (BB * HH);
      #pragma unroll
      for (int r = 0; r < 16; ++r) {
        int m = mrow + (r & 3) + 8 * (r >> 2);
        float g = sigm(acc[r]);
        float hp = __builtin_bit_cast(float, hv[r] << 16);
        bf16 a = (bf16)(g * hp);
        st_u16(ad + (size_t)m * HH + p, (unsigned)__builtin_bit_cast(unsigned short, a));
      }
      asm volatile("s_waitcnt vmcnt(0)" ::: "memory");
      __syncthreads();
      if (tid == 0) st_stamp(astamp + wg, (unsigned)(t + 1));
      if (t + 1 < LL) accN = xg(t + 1);   // shadow x-part in stamp->next-h slack
    }
  } else {
    // ================= C: cell + zl/z =================
    const int cj = wg - NR;
    const int n = cj * 32 + lr;             // hidden col
    const bool crit = (wave < 2);
    const int m0 = crit ? 32 * wave : 32 * (wave - 2);
    const int mrow = m0 + 4 * (lane >> 5);

    for (int u = tid; u < 32 * 64; u += 256) {
      int i = u >> 6, k8 = (u & 63) << 3;
      const float* s = wclhh + (size_t)(cj * 32 + i) * HH + k8;
      bf16x8 v;
      #pragma unroll
      for (int j = 0; j < 8; ++j) v[j] = (bf16)s[j];
      unsigned byte = ((unsigned)i << 10) + ((unsigned)k8 << 1);
      byte ^= ((unsigned)(i & 7) << 4);
      *(bf16x8*)((char*)wlds + byte) = v;
    }
    __syncthreads();

    const float biasc = bc[n];
    const float biaszl = bg[1024 + n];
    const float biasz = bg[2048 + n];

    auto xc = [&](int tt) {
      f32x16 a;
      #pragma unroll
      for (int r = 0; r < 16; ++r) a[r] = biasc;
      const bf16* xa = xbf + (size_t)tt * (BB * HH) + (size_t)(m0 + lr) * HH + kq;
      const bf16* wb = wcb + (size_t)n * HH + kq;
      #pragma unroll 4
      for (int kk = 0; kk < 32; ++kk) {
        bf16x8 av = *(const bf16x8*)(xa + kk * 16);
        bf16x8 bv = *(const bf16x8*)(wb + kk * 16);
        a = MFMA32(av, bv, a);
      }
      return a;
    };

    f32x16 acc, accN, azl, az, azlN, azN;
    float hreg[16];
    #pragma unroll
    for (int r = 0; r < 16; ++r) hreg[r] = 0.0f;

    if (crit) {
      accN = xc(0);
    } else {  // zl/z x-parts of step 0
      #pragma unroll
      for (int r = 0; r < 16; ++r) { azlN[r] = biaszl; azN[r] = biasz; }
      const bf16* xa = xbf + (size_t)(m0 + lr) * HH + kq;
      const bf16* w1 = wgsel + (size_t)(512 + n) * HH + kq;
      const bf16* w2 = wgsel + (size_t)(1024 + n) * HH + kq;
      #pragma unroll 4
      for (int kk = 0; kk < 32; ++kk) {
        bf16x8 av = *(const bf16x8*)(xa + kk * 16);
        azlN = MFMA32(av, *(const bf16x8*)(w1 + kk * 16), azlN);
        azN = MFMA32(av, *(const bf16x8*)(w2 + kk * 16), azN);
      }
    }

    for (int t = 0; t < LL; ++t) {
      if (crit) {
        acc = accN;
        if (t > 0) {  // a2(t) stamped with t+1
          {
            const unsigned* sp = astamp + (lane & 7);
            while (__any((int)(ld_stamp(sp) < (unsigned)(t + 1)))) {}
          }
          __builtin_amdgcn_sched_barrier(0);
          const bf16* aa = a2buf + (size_t)(t & 1) * (BB * HH) + (size_t)(m0 + lr) * HH + kq;
          bf16x8 fA[8], fB[8];
          #pragma unroll
          for (int j = 0; j < 8; ++j) ld_frag(aa + j * 16, fA[j]);
          #pragma unroll
          for (int j = 0; j < 8; ++j) ld_frag(aa + (8 + j) * 16, fB[j]);
          VWAIT(8);
          #pragma unroll
          for (int j = 0; j < 8; ++j) acc = MFMA32(fA[j], ldsfrag(wlds, lr, j * 16 + kq), acc);
          #pragma unroll
          for (int j = 0; j < 8; ++j) ld_frag(aa + (16 + j) * 16, fA[j]);
          VWAIT(8);
          #pragma unroll
          for (int j = 0; j < 8; ++j) acc = MFMA32(fB[j], ldsfrag(wlds, lr, (8 + j) * 16 + kq), acc);
          #pragma unroll
          for (int j = 0; j < 8; ++j) ld_frag(aa + (24 + j) * 16, fB[j]);
          VWAIT(8);
          #pragma unroll
          for (int j = 0; j < 8; ++j) acc = MFMA32(fA[j], ldsfrag(wlds, lr, (16 + j) * 16 + kq), acc);
          VWAIT(0);
          #pragma unroll
          for (int j = 0; j < 8; ++j) acc = MFMA32(fB[j], ldsfrag(wlds, lr, (24 + j) * 16 + kq), acc);
        }
      } else {
        azl = azlN; az = azN;
        if (t > 0) {  // h(t-1) stamped with t
          {
            const unsigned* sp = hstamp + (lane & 15);
            while (__any((int)(ld_stamp(sp) < (unsigned)t))) {}
          }
          __builtin_amdgcn_sched_barrier(0);
          const bf16* hsA = hbuf + (size_t)((t - 1) & 1) * (BB * HH) + (size_t)(m0 + lr) * HH + kq;
          const bf16* bl = whhzz + (size_t)n * HH + kq;
          const bf16* bz = whhzz + (size_t)(512 + n) * HH + kq;
          bf16x8 A[2][4], Wl[2][4], Wz[2][4];
          #pragma unroll
          for (int j = 0; j < 4; ++j) {
            ld_frag(hsA + j * 16, A[0][j]);
            ld_frag_c(bl + j * 16, Wl[0][j]);
            ld_frag_c(bz + j * 16, Wz[0][j]);
          }
          #pragma unroll
          for (int b = 0; b < 8; ++b) {
            const int s = b & 1, ns = s ^ 1;
            if (b < 7) {
              #pragma unroll
              for (int j = 0; j < 4; ++j) {
                ld_frag(hsA + ((b + 1) * 4 + j) * 16, A[ns][j]);
                ld_frag_c(bl + ((b + 1) * 4 + j) * 16, Wl[ns][j]);
                ld_frag_c(bz + ((b + 1) * 4 + j) * 16, Wz[ns][j]);
              }
              VWAIT(12);
            } else {
              VWAIT(0);
            }
            #pragma unroll
            for (int j = 0; j < 4; ++j) {
              azl = MFMA32(A[s][j], Wl[s][j], azl);
              az = MFMA32(A[s][j], Wz[s][j], az);
            }
          }
        }
        #pragma unroll
        for (int r = 0; r < 16; ++r) {
          int m = mrow + (r & 3) + 8 * (r >> 2);
          zlzs[m * 32 + lr] = sigm(azl[r]);
          zlzs[2048 + m * 32 + lr] = sigm(az[r]);
        }
      }
      __syncthreads();  // mid: zl/z LDS ready
      if (crit) {
        bf16* hd = hbuf + (size_t)(t & 1) * (BB * HH);
        #pragma unroll
        for (int r = 0; r < 16; ++r) {
          int m = mrow + (r & 3) + 8 * (r >> 2);
          float zlv = zlzs[m * 32 + lr];
          float zv = zlzs[2048 + m * 32 + lr];
          float h = zlv * hreg[r] + zv * tanhx(acc[r]);
          hreg[r] = h;
          out[(size_t)m * (LL * HH) + (size_t)t * HH + n] = h;
          bf16 hb = (bf16)h;
          st_u16(hd + (size_t)m * HH + n, (unsigned)__builtin_bit_cast(unsigned short, hb));
        }
        asm volatile("s_waitcnt vmcnt(0)" ::: "memory");
      }
      __syncthreads();  // end: h published by all crit waves
      if (tid == 0) st_stamp(hstamp + cj, (unsigned)(t + 1));
      if (t + 1 < LL) {  // shadow x-parts
        if (crit) {
          accN = xc(t + 1);
        } else {
          #pragma unroll
          for (int r = 0; r < 16; ++r) { azlN[r] = biaszl; azN[r] = biasz; }
          const bf16* xa = xbf + (size_t)(t + 1) * (BB * HH) + (size_t)(m0 + lr) * HH + kq;
          const bf16* w1 = wgsel + (size_t)(512 + n) * HH + kq;
          const bf16* w2 = wgsel + (size_t)(1024 + n) * HH + kq;
          #pragma unroll 4
          for (int kk = 0; kk < 32; ++kk) {
            bf16x8 av = *(const bf16x8*)(xa + kk * 16);
            azlN = MFMA32(av, *(const bf16x8*)(w1 + kk * 16), azlN);
            azN = MFMA32(av, *(const bf16x8*)(w2 + kk * 16), azN);
          }
        }
      }
    }
  }
}

extern "C" void kernel_launch(void* const* d_in, const int* in_sizes, int n_in,
                              void* d_out, int out_size, void* d_ws, size_t ws_size,
                              hipStream_t stream) {
  (void)in_sizes; (void)n_in; (void)out_size; (void)ws_size;
  const float* x     = (const float*)d_in[0];
  const float* wgih  = (const float*)d_in[2];
  const float* bg    = (const float*)d_in[3];
  const float* wglhh = (const float*)d_in[4];
  const float* wcihf = (const float*)d_in[6];
  const float* bc    = (const float*)d_in[7];
  const float* wclhh = (const float*)d_in[8];
  float* out = (float*)d_out;

  char* ws = (char*)d_ws;
  bf16* xbf     = (bf16*)(ws + OFF_X);
  bf16* wgsel   = (bf16*)(ws + OFF_WGSEL);
  bf16* wcb     = (bf16*)(ws + OFF_WCIH);
  bf16* whhzz   = (bf16*)(ws + OFF_WHHZZ);
  bf16* hbuf    = (bf16*)(ws + OFF_HBUF);
  bf16* a2buf   = (bf16*)(ws + OFF_A2);
  unsigned* ctr = (unsigned*)(ws + OFF_CTR);

  hipMemsetAsync(ctr, 0, 512, stream);  // stamps must restart at 0 every replay
  hipMemsetAsync(out + (size_t)BB * LL * HH, 0, (size_t)BB * HH * sizeof(float), stream);

  k_cvt_x<<<dim3(32768), dim3(256), 0, stream>>>(x, xbf);
  k_cvt_w<<<dim3(1536), dim3(256), 0, stream>>>(wgih, wcihf, wglhh, wgsel, wcb, whhzz);
  k_main<<<dim3(NR + NC), dim3(256), 0, stream>>>(xbf, wgsel, wcb, whhzz, wglhh, wclhh,
                                                  bg, bc, out, hbuf, a2buf, ctr);
}

// Round 6
// 22512.228 us; speedup vs baseline: 1.6517x; 1.0083x over previous
//
#include <hip/hip_runtime.h>
#include <hip/hip_bf16.h>
#include <stdint.h>

typedef __bf16 bf16;
typedef __bf16 bf16x8 __attribute__((ext_vector_type(8)));
typedef __bf16 bf16x4 __attribute__((ext_vector_type(4)));
typedef float f32x16 __attribute__((ext_vector_type(16)));

#define LL 1024
#define BB 64
#define HH 512
#define NR 8    // rl WGs, 64 gate-cols each
#define NC 16   // cell WGs, 32 hidden-cols each
#define NWG (NR + NC)
#define NLAUNCH 192   // 24 workers + 168 clock-boost fillers (1 block/CU, all resident)
#define MFMA32(a, b, c) __builtin_amdgcn_mfma_f32_32x32x16_bf16(a, b, c, 0, 0, 0)

// ---------------- ws layout (bytes) ----------------
#define OFF_X      ((size_t)0)           // [LL][BB][HH] bf16       67,108,864
#define OFF_WGSEL  ((size_t)67108864)    // [1536][512] bf16 (x-side rl,zl,z)
#define OFF_WCIH   ((size_t)68681728)    // [512][512]  bf16 (x-side cell)
#define OFF_WHHZZ  ((size_t)69206016)    // [1024][512] bf16 (h-side zl,z)
#define OFF_HBUF   ((size_t)70254592)    // [2][64][512] bf16
#define OFF_A2     ((size_t)70385664)    // [2][64][512] bf16
#define OFF_CTR    ((size_t)70516736)    // astamp[8]@0, hstamp[16]@64B, done@256B

static __device__ __forceinline__ float sigm(float x) {
  return 1.0f / (1.0f + __expf(-x));
}
static __device__ __forceinline__ float tanhx(float x) {
  x = fminf(15.0f, fmaxf(-15.0f, x));
  float e = __expf(2.0f * x);
  return (e - 1.0f) / (e + 1.0f);
}

// ---- raw vmem helpers (manual vmcnt accounting; FIFO completion order).
// NOTE: counted VWAIT(N) is only valid while the kernel is spill-free
// (scratch traffic would also bump vmcnt) — R5 lesson. Keep batches 8-wide.
static __device__ __forceinline__ unsigned ld_stamp(const unsigned* p) {
  unsigned s;
  asm volatile("global_load_dword %0, %1, off sc0 sc1\n\ts_waitcnt vmcnt(0)"
               : "=v"(s) : "v"(p) : "memory");
  return s;
}
static __device__ __forceinline__ void st_stamp(unsigned* p, unsigned v) {
  asm volatile("global_store_dword %0, %1, off sc0 sc1" :: "v"(p), "v"(v) : "memory");
}
static __device__ __forceinline__ void ld_frag(const bf16* p, bf16x8& d) {
  asm volatile("global_load_dwordx4 %0, %1, off sc0 sc1" : "=v"(d) : "v"(p) : "memory");
}
static __device__ __forceinline__ void ld_frag_c(const bf16* p, bf16x8& d) {  // cached
  asm volatile("global_load_dwordx4 %0, %1, off" : "=v"(d) : "v"(p) : "memory");
}
static __device__ __forceinline__ void ld_u16(const bf16* p, unsigned& d) {
  asm volatile("global_load_ushort %0, %1, off sc0 sc1" : "=v"(d) : "v"(p) : "memory");
}
static __device__ __forceinline__ void st_u16(bf16* p, unsigned v) {
  asm volatile("global_store_short %0, %1, off sc0 sc1" :: "v"(p), "v"(v) : "memory");
}
#define VWAIT(n) do { asm volatile("s_waitcnt vmcnt(" #n ")" ::: "memory"); \
                      __builtin_amdgcn_sched_barrier(0); } while (0)

// swizzled LDS b-frag read: row i, 8 consecutive k; byte ^= (i&7)<<4
static __device__ __forceinline__ bf16x8 ldsfrag(const bf16* w, int i, int k) {
  unsigned byte = ((unsigned)i << 10) + ((unsigned)k << 1);
  byte ^= ((unsigned)(i & 7) << 4);
  return *(const bf16x8*)((const char*)w + byte);
}

__global__ __launch_bounds__(256) void k_cvt_x(const float* __restrict__ in,
                                               bf16* __restrict__ o) {
  size_t i = ((size_t)blockIdx.x * 256 + threadIdx.x) * 4;
  float4 f = *(const float4*)(in + i);
  bf16x4 v;
  v[0] = (bf16)f.x; v[1] = (bf16)f.y; v[2] = (bf16)f.z; v[3] = (bf16)f.w;
  *(bf16x4*)(o + i) = v;
}

// wgsel: rows {rl:0..511 -> W_gih[0..511], zl:512..1023 -> W_gih[1024..1535],
//              z:1024..1535 -> W_gih[2048..2559]}
// wcb:   W_cih
// whhzz: rows {zl:0..511 -> W_glhh[1024..1535], z:512..1023 -> W_glhh[2048..2559]}
__global__ __launch_bounds__(256) void k_cvt_w(const float* __restrict__ wgih,
                                               const float* __restrict__ wcf,
                                               const float* __restrict__ wglhh,
                                               bf16* __restrict__ wgsel,
                                               bf16* __restrict__ wcb,
                                               bf16* __restrict__ whhzz) {
  int i = blockIdx.x * 256 + threadIdx.x;
  const int NQ1 = (1536 * 512) / 4;
  const int NQ2 = (512 * 512) / 4;
  const float* s;
  bf16* d;
  if (i < NQ1) {
    int e = i * 4;
    int p = e >> 9, k = e & 511;
    int src = (p < 512) ? p : ((p < 1024) ? (1024 + p - 512) : (2048 + p - 1024));
    s = wgih + (size_t)src * 512 + k;
    d = wgsel + (size_t)p * 512 + k;
  } else if (i < NQ1 + NQ2) {
    int e = (i - NQ1) * 4;
    int n = e >> 9, k = e & 511;
    s = wcf + (size_t)n * 512 + k;
    d = wcb + (size_t)n * 512 + k;
  } else {
    int e = (i - NQ1 - NQ2) * 4;
    int q = e >> 9, k = e & 511;
    int src = (q < 512) ? (1024 + q) : (2048 + q - 512);
    s = wglhh + (size_t)src * 512 + k;
    d = whhzz + (size_t)q * 512 + k;
  }
  float4 f = *(const float4*)s;
  bf16x4 v;
  v[0] = (bf16)f.x; v[1] = (bf16)f.y; v[2] = (bf16)f.z; v[3] = (bf16)f.w;
  *(bf16x4*)d = v;
}

// Persistent recurrence: 24 worker WGs + 168 clock-boost fillers, 256 thr.
// WGs 0..7  (R): rl gates, 64 cols each; 4 waves = 2 row-tiles x 2 col-tiles.
// WGs 8..23 (C): 32 hidden cols each; waves 0-1 cell, waves 2-3 zl/z.
__global__ __launch_bounds__(256) void k_main(
    const bf16* __restrict__ xbf, const bf16* __restrict__ wgsel,
    const bf16* __restrict__ wcb, const bf16* __restrict__ whhzz,
    const float* __restrict__ wglhh, const float* __restrict__ wclhh,
    const float* __restrict__ bg, const float* __restrict__ bc,
    float* __restrict__ out, bf16* __restrict__ hbuf,
    bf16* __restrict__ a2buf, unsigned* __restrict__ ctrs) {
  __shared__ __align__(16) char smem[64 * 1024];
  bf16* wlds = (bf16*)smem;                     // R: 64KB weights; C: 32KB
  float* zlzs = (float*)(smem + 32 * 1024);     // C: [2][64][32] f32 (16KB)

  const int wg = blockIdx.x, tid = threadIdx.x;
  unsigned* astamp = ctrs;        // 8 u32
  unsigned* hstamp = ctrs + 16;   // 16 u32
  unsigned* done = ctrs + 64;     // byte 256

  if (wg >= NWG) {  // ---- filler: hold DPM clocks high until workers finish --
    float a0 = 1.0f + tid, a1 = 2.0f, a2v = 3.0f, a3 = 4.0f;
    const float b0 = 1.0000001f, c0 = 1e-7f;
    for (unsigned it = 0;; ++it) {
      #pragma unroll 16
      for (int u = 0; u < 16; ++u) {
        a0 = __builtin_fmaf(a0, b0, c0);
        a1 = __builtin_fmaf(a1, b0, -c0);
        a2v = __builtin_fmaf(a2v, b0, c0);
        a3 = __builtin_fmaf(a3, b0, -c0);
      }
      if ((it & 255u) == 0u) { if (ld_stamp(done) != 0u) break; }
    }
    asm volatile("" :: "v"(a0), "v"(a1), "v"(a2v), "v"(a3));
    return;
  }
  __builtin_amdgcn_s_setprio(1);  // workers beat fillers at issue arbitration

  const int lane = tid & 63, wave = tid >> 6;
  const int lr = lane & 31, kq = (lane >> 5) * 8;

  if (wg < NR) {
    // ================= R: rl gates =================
    const int m0 = 32 * (wave & 1);
    const int lc = 32 * (wave >> 1) + lr;   // local weight row 0..63
    const int p = wg * 64 + lc;             // rl col 0..511
    const int mrow = m0 + 4 * (lane >> 5);
    const float bias = bg[p];

    for (int u = tid; u < 64 * 64; u += 256) {
      int i = u >> 6, k8 = (u & 63) << 3;
      const float* s = wglhh + (size_t)(wg * 64 + i) * HH + k8;
      bf16x8 v;
      #pragma unroll
      for (int j = 0; j < 8; ++j) v[j] = (bf16)s[j];
      unsigned byte = ((unsigned)i << 10) + ((unsigned)k8 << 1);
      byte ^= ((unsigned)(i & 7) << 4);
      *(bf16x8*)((char*)wlds + byte) = v;
    }
    __syncthreads();

    auto xg = [&](int tt) {
      f32x16 a;
      #pragma unroll
      for (int r = 0; r < 16; ++r) a[r] = bias;
      const bf16* xa = xbf + (size_t)tt * (BB * HH) + (size_t)(m0 + lr) * HH + kq;
      const bf16* wb = wgsel + (size_t)p * HH + kq;
      #pragma unroll 4
      for (int kk = 0; kk < 32; ++kk) {
        bf16x8 av = *(const bf16x8*)(xa + kk * 16);
        bf16x8 bv = *(const bf16x8*)(wb + kk * 16);
        a = MFMA32(av, bv, a);
      }
      return a;
    };

    f32x16 accN = xg(1);                     // rl(0) unused: a2(0)==0
    for (int t = 1; t < LL; ++t) {
      f32x16 acc = accN;
      {  // poll h(t-1): stamps hold last-published-step+1
        const unsigned* sp = hstamp + (lane & 15);
        while (__any((int)(ld_stamp(sp) < (unsigned)t))) {}
      }
      __builtin_amdgcn_sched_barrier(0);
      const bf16* hs = hbuf + (size_t)((t - 1) & 1) * (BB * HH);
      const bf16* ha = hs + (size_t)(m0 + lr) * HH + kq;
      bf16x8 fA[8], fB[8];
      unsigned hv[16];
      // FIFO plan: fA(0-7) fB(8-15) | w8 | MFMA0 | fA(16-23) | w8 | MFMA1
      //            fB(24-31) u16x16 | w24 | MFMA2 | w16 | MFMA3 | w0
      #pragma unroll
      for (int j = 0; j < 8; ++j) ld_frag(ha + j * 16, fA[j]);
      #pragma unroll
      for (int j = 0; j < 8; ++j) ld_frag(ha + (8 + j) * 16, fB[j]);
      VWAIT(8);
      #pragma unroll
      for (int j = 0; j < 8; ++j) acc = MFMA32(fA[j], ldsfrag(wlds, lc, j * 16 + kq), acc);
      #pragma unroll
      for (int j = 0; j < 8; ++j) ld_frag(ha + (16 + j) * 16, fA[j]);
      VWAIT(8);
      #pragma unroll
      for (int j = 0; j < 8; ++j) acc = MFMA32(fB[j], ldsfrag(wlds, lc, (8 + j) * 16 + kq), acc);
      #pragma unroll
      for (int j = 0; j < 8; ++j) ld_frag(ha + (24 + j) * 16, fB[j]);
      #pragma unroll
      for (int r = 0; r < 16; ++r) {
        int m = mrow + (r & 3) + 8 * (r >> 2);
        ld_u16(hs + (size_t)m * HH + p, hv[r]);
      }
      VWAIT(24);
      #pragma unroll
      for (int j = 0; j < 8; ++j) acc = MFMA32(fA[j], ldsfrag(wlds, lc, (16 + j) * 16 + kq), acc);
      VWAIT(16);
      #pragma unroll
      for (int j = 0; j < 8; ++j) acc = MFMA32(fB[j], ldsfrag(wlds, lc, (24 + j) * 16 + kq), acc);
      VWAIT(0);
      // publish a2 = sigm(rl) * h_prev(bf16)
      bf16* ad = a2buf + (size_t)(t & 1) * (BB * HH);
      #pragma unroll
      for (int r = 0; r < 16; ++r) {
        int m = mrow + (r & 3) + 8 * (r >> 2);
        float g = sigm(acc[r]);
        float hp = __builtin_bit_cast(float, hv[r] << 16);
        bf16 a = (bf16)(g * hp);
        st_u16(ad + (size_t)m * HH + p, (unsigned)__builtin_bit_cast(unsigned short, a));
      }
      asm volatile("s_waitcnt vmcnt(0)" ::: "memory");
      __syncthreads();
      if (tid == 0) st_stamp(astamp + wg, (unsigned)(t + 1));
      if (t + 1 < LL) accN = xg(t + 1);   // shadow x-part in stamp->next-h slack
    }
  } else {
    // ================= C: cell + zl/z =================
    const int cj = wg - NR;
    const int n = cj * 32 + lr;             // hidden col
    const bool crit = (wave < 2);
    const int m0 = crit ? 32 * wave : 32 * (wave - 2);
    const int mrow = m0 + 4 * (lane >> 5);

    for (int u = tid; u < 32 * 64; u += 256) {
      int i = u >> 6, k8 = (u & 63) << 3;
      const float* s = wclhh + (size_t)(cj * 32 + i) * HH + k8;
      bf16x8 v;
      #pragma unroll
      for (int j = 0; j < 8; ++j) v[j] = (bf16)s[j];
      unsigned byte = ((unsigned)i << 10) + ((unsigned)k8 << 1);
      byte ^= ((unsigned)(i & 7) << 4);
      *(bf16x8*)((char*)wlds + byte) = v;
    }
    __syncthreads();

    const float biasc = bc[n];
    const float biaszl = bg[1024 + n];
    const float biasz = bg[2048 + n];

    auto xc = [&](int tt) {
      f32x16 a;
      #pragma unroll
      for (int r = 0; r < 16; ++r) a[r] = biasc;
      const bf16* xa = xbf + (size_t)tt * (BB * HH) + (size_t)(m0 + lr) * HH + kq;
      const bf16* wb = wcb + (size_t)n * HH + kq;
      #pragma unroll 4
      for (int kk = 0; kk < 32; ++kk) {
        bf16x8 av = *(const bf16x8*)(xa + kk * 16);
        bf16x8 bv = *(const bf16x8*)(wb + kk * 16);
        a = MFMA32(av, bv, a);
      }
      return a;
    };

    f32x16 acc, accN, azl, az, azlN, azN;
    float hreg[16];
    #pragma unroll
    for (int r = 0; r < 16; ++r) hreg[r] = 0.0f;

    if (crit) {
      accN = xc(0);
    } else {  // zl/z x-parts of step 0
      #pragma unroll
      for (int r = 0; r < 16; ++r) { azlN[r] = biaszl; azN[r] = biasz; }
      const bf16* xa = xbf + (size_t)(m0 + lr) * HH + kq;
      const bf16* w1 = wgsel + (size_t)(512 + n) * HH + kq;
      const bf16* w2 = wgsel + (size_t)(1024 + n) * HH + kq;
      #pragma unroll 4
      for (int kk = 0; kk < 32; ++kk) {
        bf16x8 av = *(const bf16x8*)(xa + kk * 16);
        azlN = MFMA32(av, *(const bf16x8*)(w1 + kk * 16), azlN);
        azN = MFMA32(av, *(const bf16x8*)(w2 + kk * 16), azN);
      }
    }

    for (int t = 0; t < LL; ++t) {
      if (crit) {
        acc = accN;
        f32x16 acc1;
        #pragma unroll
        for (int r = 0; r < 16; ++r) acc1[r] = 0.0f;
        if (t > 0) {  // a2(t) stamped with t+1
          {
            const unsigned* sp = astamp + (lane & 7);
            while (__any((int)(ld_stamp(sp) < (unsigned)(t + 1)))) {}
          }
          __builtin_amdgcn_sched_barrier(0);
          const bf16* aa = a2buf + (size_t)(t & 1) * (BB * HH) + (size_t)(m0 + lr) * HH + kq;
          bf16x8 fA[8], fB[8];
          #pragma unroll
          for (int j = 0; j < 8; ++j) ld_frag(aa + j * 16, fA[j]);
          #pragma unroll
          for (int j = 0; j < 8; ++j) ld_frag(aa + (8 + j) * 16, fB[j]);
          VWAIT(8);
          #pragma unroll
          for (int j = 0; j < 8; ++j) {
            if (j & 1) acc1 = MFMA32(fA[j], ldsfrag(wlds, lr, j * 16 + kq), acc1);
            else       acc  = MFMA32(fA[j], ldsfrag(wlds, lr, j * 16 + kq), acc);
          }
          #pragma unroll
          for (int j = 0; j < 8; ++j) ld_frag(aa + (16 + j) * 16, fA[j]);
          VWAIT(8);
          #pragma unroll
          for (int j = 0; j < 8; ++j) {
            if (j & 1) acc1 = MFMA32(fB[j], ldsfrag(wlds, lr, (8 + j) * 16 + kq), acc1);
            else       acc  = MFMA32(fB[j], ldsfrag(wlds, lr, (8 + j) * 16 + kq), acc);
          }
          #pragma unroll
          for (int j = 0; j < 8; ++j) ld_frag(aa + (24 + j) * 16, fB[j]);
          VWAIT(8);
          #pragma unroll
          for (int j = 0; j < 8; ++j) {
            if (j & 1) acc1 = MFMA32(fA[j], ldsfrag(wlds, lr, (16 + j) * 16 + kq), acc1);
            else       acc  = MFMA32(fA[j], ldsfrag(wlds, lr, (16 + j) * 16 + kq), acc);
          }
          VWAIT(0);
          #pragma unroll
          for (int j = 0; j < 8; ++j) {
            if (j & 1) acc1 = MFMA32(fB[j], ldsfrag(wlds, lr, (24 + j) * 16 + kq), acc1);
            else       acc  = MFMA32(fB[j], ldsfrag(wlds, lr, (24 + j) * 16 + kq), acc);
          }
        }
        #pragma unroll
        for (int r = 0; r < 16; ++r) acc[r] += acc1[r];
      } else {
        azl = azlN; az = azN;
        if (t > 0) {  // h(t-1) stamped with t
          {
            const unsigned* sp = hstamp + (lane & 15);
            while (__any((int)(ld_stamp(sp) < (unsigned)t))) {}
          }
          __builtin_amdgcn_sched_barrier(0);
          const bf16* hsA = hbuf + (size_t)((t - 1) & 1) * (BB * HH) + (size_t)(m0 + lr) * HH + kq;
          const bf16* bl = whhzz + (size_t)n * HH + kq;
          const bf16* bz = whhzz + (size_t)(512 + n) * HH + kq;
          bf16x8 A[2][4], Wl[2][4], Wz[2][4];
          #pragma unroll
          for (int j = 0; j < 4; ++j) {
            ld_frag(hsA + j * 16, A[0][j]);
            ld_frag_c(bl + j * 16, Wl[0][j]);
            ld_frag_c(bz + j * 16, Wz[0][j]);
          }
          #pragma unroll
          for (int b = 0; b < 8; ++b) {
            const int s = b & 1, ns = s ^ 1;
            if (b < 7) {
              #pragma unroll
              for (int j = 0; j < 4; ++j) {
                ld_frag(hsA + ((b + 1) * 4 + j) * 16, A[ns][j]);
                ld_frag_c(bl + ((b + 1) * 4 + j) * 16, Wl[ns][j]);
                ld_frag_c(bz + ((b + 1) * 4 + j) * 16, Wz[ns][j]);
              }
              VWAIT(12);
            } else {
              VWAIT(0);
            }
            #pragma unroll
            for (int j = 0; j < 4; ++j) {
              azl = MFMA32(A[s][j], Wl[s][j], azl);
              az = MFMA32(A[s][j], Wz[s][j], az);
            }
          }
        }
        #pragma unroll
        for (int r = 0; r < 16; ++r) {
          int m = mrow + (r & 3) + 8 * (r >> 2);
          zlzs[m * 32 + lr] = sigm(azl[r]);
          zlzs[2048 + m * 32 + lr] = sigm(az[r]);
        }
      }
      __syncthreads();  // mid: zl/z LDS ready
      if (crit) {
        bf16* hd = hbuf + (size_t)(t & 1) * (BB * HH);
        #pragma unroll
        for (int r = 0; r < 16; ++r) {
          int m = mrow + (r & 3) + 8 * (r >> 2);
          float zlv = zlzs[m * 32 + lr];
          float zv = zlzs[2048 + m * 32 + lr];
          float h = zlv * hreg[r] + zv * tanhx(acc[r]);
          hreg[r] = h;
          bf16 hb = (bf16)h;
          st_u16(hd + (size_t)m * HH + n, (unsigned)__builtin_bit_cast(unsigned short, hb));
        }
        asm volatile("s_waitcnt vmcnt(0)" ::: "memory");
      }
      __syncthreads();  // end: h published by all crit waves
      if (tid == 0) st_stamp(hstamp + cj, (unsigned)(t + 1));
      if (crit) {
        // fp32 outputs AFTER the stamp — off the serial chain. Next pollge's
        // internal vmcnt(0) re-zeroes the FIFO accounting before counted waits.
        #pragma unroll
        for (int r = 0; r < 16; ++r) {
          int m = mrow + (r & 3) + 8 * (r >> 2);
          out[(size_t)m * (LL * HH) + (size_t)t * HH + n] = hreg[r];
        }
      }
      if (t + 1 < LL) {  // shadow x-parts
        if (crit) {
          accN = xc(t + 1);
        } else {
          #pragma unroll
          for (int r = 0; r < 16; ++r) { azlN[r] = biaszl; azN[r] = biasz; }
          const bf16* xa = xbf + (size_t)(t + 1) * (BB * HH) + (size_t)(m0 + lr) * HH + kq;
          const bf16* w1 = wgsel + (size_t)(512 + n) * HH + kq;
          const bf16* w2 = wgsel + (size_t)(1024 + n) * HH + kq;
          #pragma unroll 4
          for (int kk = 0; kk < 32; ++kk) {
            bf16x8 av = *(const bf16x8*)(xa + kk * 16);
            azlN = MFMA32(av, *(const bf16x8*)(w1 + kk * 16), azlN);
            azN = MFMA32(av, *(const bf16x8*)(w2 + kk * 16), azN);
          }
        }
      }
    }
    if (cj == 0 && tid == 0) st_stamp(done, 1u);  // release the fillers
  }
}

extern "C" void kernel_launch(void* const* d_in, const int* in_sizes, int n_in,
                              void* d_out, int out_size, void* d_ws, size_t ws_size,
                              hipStream_t stream) {
  (void)in_sizes; (void)n_in; (void)out_size; (void)ws_size;
  const float* x     = (const float*)d_in[0];
  const float* wgih  = (const float*)d_in[2];
  const float* bg    = (const float*)d_in[3];
  const float* wglhh = (const float*)d_in[4];
  const float* wcihf = (const float*)d_in[6];
  const float* bc    = (const float*)d_in[7];
  const float* wclhh = (const float*)d_in[8];
  float* out = (float*)d_out;

  char* ws = (char*)d_ws;
  bf16* xbf     = (bf16*)(ws + OFF_X);
  bf16* wgsel   = (bf16*)(ws + OFF_WGSEL);
  bf16* wcb     = (bf16*)(ws + OFF_WCIH);
  bf16* whhzz   = (bf16*)(ws + OFF_WHHZZ);
  bf16* hbuf    = (bf16*)(ws + OFF_HBUF);
  bf16* a2buf   = (bf16*)(ws + OFF_A2);
  unsigned* ctr = (unsigned*)(ws + OFF_CTR);

  hipMemsetAsync(ctr, 0, 512, stream);  // stamps + done reset every replay
  hipMemsetAsync(out + (size_t)BB * LL * HH, 0, (size_t)BB * HH * sizeof(float), stream);

  k_cvt_x<<<dim3(32768), dim3(256), 0, stream>>>(x, xbf);
  k_cvt_w<<<dim3(1536), dim3(256), 0, stream>>>(wgih, wcihf, wglhh, wgsel, wcb, whhzz);
  k_main<<<dim3(NLAUNCH), dim3(256), 0, stream>>>(xbf, wgsel, wcb, whhzz, wglhh, wclhh,
                                                  bg, bc, out, hbuf, a2buf, ctr);
}

// Round 9
// 14292.284 us; speedup vs baseline: 2.6016x; 1.5751x over previous
//
#include <hip/hip_runtime.h>
#include <hip/hip_bf16.h>
#include <stdint.h>

typedef __bf16 bf16;
typedef __bf16 bf16x8 __attribute__((ext_vector_type(8)));
typedef __bf16 bf16x4 __attribute__((ext_vector_type(4)));
typedef float f32x16 __attribute__((ext_vector_type(16)));
typedef float f32x4 __attribute__((ext_vector_type(4)));

#define LL 1024
#define BB 64
#define HH 512
#define NR 8    // rl WGs, 64 gate-cols each
#define NC 16   // cell WGs, 32 hidden-cols each
#define NWG (NR + NC)
#define NPROD 32              // producer WGs (128 waves = 128 x-proj tiles)
#define NLAUNCH (NWG + NPROD)
#define WSLOT 16              // x-projection ring depth (steps)
#define MFMA32(a, b, c) __builtin_amdgcn_mfma_f32_32x32x16_bf16(a, b, c, 0, 0, 0)

// ---------------- ws layout (bytes) ----------------
#define OFF_X      ((size_t)0)           // [LL][BB][HH] bf16       67,108,864
#define OFF_WGSEL  ((size_t)67108864)    // [1536][512] bf16 (x-side rl,zl,z)
#define OFF_WCIH   ((size_t)68681728)    // [512][512]  bf16 (x-side cell)
#define OFF_WHHZZ  ((size_t)69206016)    // [1024][512] bf16 (h-side zl,z)
#define OFF_HBUF   ((size_t)70254592)    // [2][64][512] bf16
#define OFF_A2     ((size_t)70385664)    // [2][64][512] bf16
#define OFF_CTR    ((size_t)70516736)    // astamp[8]@0, hstamp[16]@64B, xstamp[128]@256B
#define OFF_XS     ((size_t)70517760)    // [WSLOT][128 tiles][64 lanes][16] f32 = 8,388,608

static __device__ __forceinline__ float sigm(float x) {
  return 1.0f / (1.0f + __expf(-x));
}
static __device__ __forceinline__ float tanhx(float x) {
  x = fminf(15.0f, fmaxf(-15.0f, x));
  float e = __expf(2.0f * x);
  return (e - 1.0f) / (e + 1.0f);
}

// ---- MALL-coherent vmem helpers (R3/R6-proven protocol) ----
static __device__ __forceinline__ unsigned ld_stamp(const unsigned* p) {
  unsigned s;
  asm volatile("global_load_dword %0, %1, off sc0 sc1\n\ts_waitcnt vmcnt(0)"
               : "=v"(s) : "v"(p) : "memory");
  return s;
}
static __device__ __forceinline__ void st_stamp(unsigned* p, unsigned v) {
  asm volatile("global_store_dword %0, %1, off sc0 sc1" :: "v"(p), "v"(v) : "memory");
}
static __device__ __forceinline__ void ld_frag(const bf16* p, bf16x8& d) {
  asm volatile("global_load_dwordx4 %0, %1, off sc0 sc1" : "=v"(d) : "v"(p) : "memory");
}
static __device__ __forceinline__ void ld_frag_c(const bf16* p, bf16x8& d) {  // cached
  asm volatile("global_load_dwordx4 %0, %1, off" : "=v"(d) : "v"(p) : "memory");
}
static __device__ __forceinline__ void ld_f4(const float* p, f32x4& d) {
  asm volatile("global_load_dwordx4 %0, %1, off sc0 sc1" : "=v"(d) : "v"(p) : "memory");
}
static __device__ __forceinline__ void st_f4(float* p, f32x4 v) {
  asm volatile("global_store_dwordx4 %0, %1, off sc0 sc1" :: "v"(p), "v"(v) : "memory");
}
static __device__ __forceinline__ void ld_u16(const bf16* p, unsigned& d) {
  asm volatile("global_load_ushort %0, %1, off sc0 sc1" : "=v"(d) : "v"(p) : "memory");
}
static __device__ __forceinline__ void st_u16(bf16* p, unsigned v) {
  asm volatile("global_store_short %0, %1, off sc0 sc1" :: "v"(p), "v"(v) : "memory");
}
#define VWAIT(n) do { asm volatile("s_waitcnt vmcnt(" #n ")" ::: "memory"); \
                      __builtin_amdgcn_sched_barrier(0); } while (0)

// swizzled LDS b-frag read: row i, 8 consecutive k; byte ^= (i&7)<<4
static __device__ __forceinline__ bf16x8 ldsfrag(const bf16* w, int i, int k) {
  unsigned byte = ((unsigned)i << 10) + ((unsigned)k << 1);
  byte ^= ((unsigned)(i & 7) << 4);
  return *(const bf16x8*)((const char*)w + byte);
}

__global__ __launch_bounds__(256) void k_cvt_x(const float* __restrict__ in,
                                               bf16* __restrict__ o) {
  size_t i = ((size_t)blockIdx.x * 256 + threadIdx.x) * 4;
  float4 f = *(const float4*)(in + i);
  bf16x4 v;
  v[0] = (bf16)f.x; v[1] = (bf16)f.y; v[2] = (bf16)f.z; v[3] = (bf16)f.w;
  *(bf16x4*)(o + i) = v;
}

// wgsel: rows {rl:0..511 -> W_gih[0..511], zl:512..1023 -> W_gih[1024..1535],
//              z:1024..1535 -> W_gih[2048..2559]}; wcb = W_cih;
// whhzz: rows {zl:0..511 -> W_glhh[1024..1535], z:512..1023 -> W_glhh[2048..2559]}
__global__ __launch_bounds__(256) void k_cvt_w(const float* __restrict__ wgih,
                                               const float* __restrict__ wcf,
                                               const float* __restrict__ wglhh,
                                               bf16* __restrict__ wgsel,
                                               bf16* __restrict__ wcb,
                                               bf16* __restrict__ whhzz) {
  int i = blockIdx.x * 256 + threadIdx.x;
  const int NQ1 = (1536 * 512) / 4;
  const int NQ2 = (512 * 512) / 4;
  const float* s;
  bf16* d;
  if (i < NQ1) {
    int e = i * 4;
    int p = e >> 9, k = e & 511;
    int src = (p < 512) ? p : ((p < 1024) ? (1024 + p - 512) : (2048 + p - 1024));
    s = wgih + (size_t)src * 512 + k;
    d = wgsel + (size_t)p * 512 + k;
  } else if (i < NQ1 + NQ2) {
    int e = (i - NQ1) * 4;
    int n = e >> 9, k = e & 511;
    s = wcf + (size_t)n * 512 + k;
    d = wcb + (size_t)n * 512 + k;
  } else {
    int e = (i - NQ1 - NQ2) * 4;
    int q = e >> 9, k = e & 511;
    int src = (q < 512) ? (1024 + q) : (2048 + q - 512);
    s = wglhh + (size_t)src * 512 + k;
    d = whhzz + (size_t)q * 512 + k;
  }
  float4 f = *(const float4*)s;
  bf16x4 v;
  v[0] = (bf16)f.x; v[1] = (bf16)f.y; v[2] = (bf16)f.z; v[3] = (bf16)f.w;
  *(bf16x4*)d = v;
}

// Persistent recurrence: 24 worker WGs (R6-proven handoff code) + 32 producer
// WGs computing ALL x-projections (bias included) into a WSLOT-deep ring.
// Tile id g in [0,128): proj = g>>5 {0 rl,1 zl,2 z,3 cell}, Msel = (g>>4)&1,
// colblock = g&15. xs[slot][g][lane][16] f32 in the consumer acc layout.
__global__ __launch_bounds__(256) void k_main(
    const bf16* __restrict__ xbf, const bf16* __restrict__ wgsel,
    const bf16* __restrict__ wcb, const bf16* __restrict__ whhzz,
    const float* __restrict__ wglhh, const float* __restrict__ wclhh,
    const float* __restrict__ bg, const float* __restrict__ bc,
    float* __restrict__ out, bf16* __restrict__ hbuf,
    bf16* __restrict__ a2buf, float* __restrict__ xs,
    unsigned* __restrict__ ctrs) {
  __shared__ __align__(16) char smem[64 * 1024];
  bf16* wlds = (bf16*)smem;                     // R: 64KB weights; C: 32KB
  float* zlzs = (float*)(smem + 32 * 1024);     // C: [2][64][32] f32 (16KB)

  const int wg = blockIdx.x, tid = threadIdx.x;
  const int lane = tid & 63, wave = tid >> 6;
  const int lr = lane & 31, kq = (lane >> 5) * 8;
  unsigned* astamp = ctrs;        // 8 u32 @0
  unsigned* hstamp = ctrs + 16;   // 16 u32 @64B
  unsigned* xstamp = ctrs + 64;   // 128 u32 @256B

  if (wg >= NWG) {
    // ================= producers: x-projections, 16 steps ahead ============
    const int gx = (wg - NWG) * 4 + wave;       // tile 0..127
    const int proj = gx >> 5;
    const int m0 = 32 * ((gx >> 4) & 1);
    const int col = (gx & 15) * 32 + lr;
    float bias;
    const bf16* wb;
    if (proj == 0)      { bias = bg[col];        wb = wgsel + (size_t)col * HH; }
    else if (proj == 1) { bias = bg[1024 + col]; wb = wgsel + (size_t)(512 + col) * HH; }
    else if (proj == 2) { bias = bg[2048 + col]; wb = wgsel + (size_t)(1024 + col) * HH; }
    else                { bias = bc[col];        wb = wcb + (size_t)col * HH; }
    wb += kq;
    float* xsl = xs + ((size_t)gx * 64 + lane) * 16;
    for (int t = 0; t < LL; ++t) {
      if (t >= WSLOT) {  // slot reuse: consumers must be past step t-WSLOT
        const unsigned* sp = hstamp + (lane & 15);
        while (__any((int)(ld_stamp(sp) < (unsigned)(t - WSLOT + 1)))) {}
      }
      f32x16 a;
      #pragma unroll
      for (int r = 0; r < 16; ++r) a[r] = bias;
      const bf16* xa = xbf + (size_t)t * (BB * HH) + (size_t)(m0 + lr) * HH + kq;
      #pragma unroll 4
      for (int kk = 0; kk < 32; ++kk)
        a = MFMA32(*(const bf16x8*)(xa + kk * 16), *(const bf16x8*)(wb + kk * 16), a);
      float* dst = xsl + (size_t)(t & (WSLOT - 1)) * (128 * 64 * 16);
      f32x4 v0, v1, v2, v3;
      #pragma unroll
      for (int e = 0; e < 4; ++e) { v0[e] = a[e]; v1[e] = a[4 + e]; v2[e] = a[8 + e]; v3[e] = a[12 + e]; }
      st_f4(dst, v0); st_f4(dst + 4, v1); st_f4(dst + 8, v2); st_f4(dst + 12, v3);
      asm volatile("s_waitcnt vmcnt(0)" ::: "memory");
      if (lane == 0) st_stamp(xstamp + gx, (unsigned)(t + 1));
    }
    return;
  }
  __builtin_amdgcn_s_setprio(1);  // workers beat producers at issue arbitration

  if (wg < NR) {
    // ================= R: rl gates =================
    const int m0 = 32 * (wave & 1);
    const int lc = 32 * (wave >> 1) + lr;   // local weight row 0..63
    const int p = wg * 64 + lc;             // rl col 0..511
    const int mrow = m0 + 4 * (lane >> 5);
    const int gx = (wave & 1) * 16 + 2 * wg + (wave >> 1);   // proj0 tile

    for (int u = tid; u < 64 * 64; u += 256) {
      int i = u >> 6, k8 = (u & 63) << 3;
      const float* s = wglhh + (size_t)(wg * 64 + i) * HH + k8;
      bf16x8 v;
      #pragma unroll
      for (int j = 0; j < 8; ++j) v[j] = (bf16)s[j];
      unsigned byte = ((unsigned)i << 10) + ((unsigned)k8 << 1);
      byte ^= ((unsigned)(i & 7) << 4);
      *(bf16x8*)((char*)wlds + byte) = v;
    }
    __syncthreads();

    for (int t = 1; t < LL; ++t) {
      {  // poll h(t-1) + x(t)
        const unsigned* sp = hstamp + (lane & 15);
        unsigned tgt = (unsigned)t;
        if (lane == 16) { sp = xstamp + gx; tgt = (unsigned)(t + 1); }
        while (__any((int)(ld_stamp(sp) < tgt))) {}
      }
      __builtin_amdgcn_sched_barrier(0);
      const float* xsp = xs + (((size_t)(t & (WSLOT - 1)) * 128 + gx) * 64 + lane) * 16;
      f32x4 xv0, xv1, xv2, xv3;
      ld_f4(xsp, xv0); ld_f4(xsp + 4, xv1); ld_f4(xsp + 8, xv2); ld_f4(xsp + 12, xv3);
      const bf16* hs = hbuf + (size_t)((t - 1) & 1) * (BB * HH);
      const bf16* ha = hs + (size_t)(m0 + lr) * HH + kq;
      bf16x8 fA[8], fB[8];
      unsigned hv[16];
      f32x16 acc;
      #pragma unroll
      for (int r = 0; r < 16; ++r) acc[r] = 0.0f;
      // FIFO plan (+4 xs prefix retires in first wait): xs4 fA8 fB8 | w8 | M0 |
      // fA'8 | w8 | M1 | fB'8 hv16 | w24 | M2 | w16 | M3 | w0
      #pragma unroll
      for (int j = 0; j < 8; ++j) ld_frag(ha + j * 16, fA[j]);
      #pragma unroll
      for (int j = 0; j < 8; ++j) ld_frag(ha + (8 + j) * 16, fB[j]);
      VWAIT(8);
      #pragma unroll
      for (int j = 0; j < 8; ++j) acc = MFMA32(fA[j], ldsfrag(wlds, lc, j * 16 + kq), acc);
      #pragma unroll
      for (int j = 0; j < 8; ++j) ld_frag(ha + (16 + j) * 16, fA[j]);
      VWAIT(8);
      #pragma unroll
      for (int j = 0; j < 8; ++j) acc = MFMA32(fB[j], ldsfrag(wlds, lc, (8 + j) * 16 + kq), acc);
      #pragma unroll
      for (int j = 0; j < 8; ++j) ld_frag(ha + (24 + j) * 16, fB[j]);
      #pragma unroll
      for (int r = 0; r < 16; ++r) {
        int m = mrow + (r & 3) + 8 * (r >> 2);
        ld_u16(hs + (size_t)m * HH + p, hv[r]);
      }
      VWAIT(24);
      #pragma unroll
      for (int j = 0; j < 8; ++j) acc = MFMA32(fA[j], ldsfrag(wlds, lc, (16 + j) * 16 + kq), acc);
      VWAIT(16);
      #pragma unroll
      for (int j = 0; j < 8; ++j) acc = MFMA32(fB[j], ldsfrag(wlds, lc, (24 + j) * 16 + kq), acc);
      VWAIT(0);
      // publish a2 = sigm(rl) * h_prev(bf16)
      bf16* ad = a2buf + (size_t)(t & 1) * (BB * HH);
      #pragma unroll
      for (int r = 0; r < 16; ++r) {
        int m = mrow + (r & 3) + 8 * (r >> 2);
        float xadd = (r < 4) ? xv0[r & 3] : (r < 8) ? xv1[r & 3]
                   : (r < 12) ? xv2[r & 3] : xv3[r & 3];
        float gg = sigm(acc[r] + xadd);
        float hp = __builtin_bit_cast(float, hv[r] << 16);
        bf16 a = (bf16)(gg * hp);
        st_u16(ad + (size_t)m * HH + p, (unsigned)__builtin_bit_cast(unsigned short, a));
      }
      asm volatile("s_waitcnt vmcnt(0)" ::: "memory");
      __syncthreads();
      if (tid == 0) st_stamp(astamp + wg, (unsigned)(t + 1));
    }
  } else {
    // ================= C: cell + zl/z =================
    const int cj = wg - NR;
    const int n = cj * 32 + lr;             // hidden col
    const bool crit = (wave < 2);
    const int m0 = crit ? 32 * wave : 32 * (wave - 2);
    const int mrow = m0 + 4 * (lane >> 5);
    const int Mq = (m0 >> 5) * 16;
    const int gc = 96 + Mq + cj;            // proj3 tile (cell-x)
    const int gzl = 32 + Mq + cj;           // proj1
    const int gz = 64 + Mq + cj;            // proj2

    for (int u = tid; u < 32 * 64; u += 256) {
      int i = u >> 6, k8 = (u & 63) << 3;
      const float* s = wclhh + (size_t)(cj * 32 + i) * HH + k8;
      bf16x8 v;
      #pragma unroll
      for (int j = 0; j < 8; ++j) v[j] = (bf16)s[j];
      unsigned byte = ((unsigned)i << 10) + ((unsigned)k8 << 1);
      byte ^= ((unsigned)(i & 7) << 4);
      *(bf16x8*)((char*)wlds + byte) = v;
    }
    __syncthreads();

    float hreg[16];
    #pragma unroll
    for (int r = 0; r < 16; ++r) hreg[r] = 0.0f;

    for (int t = 0; t < LL; ++t) {
      if (crit) {
        f32x16 acc, acc1;
        #pragma unroll
        for (int r = 0; r < 16; ++r) { acc[r] = 0.0f; acc1[r] = 0.0f; }
        f32x4 xv0, xv1, xv2, xv3;
        if (t > 0) {
          {  // poll a2(t) + x(t)
            const unsigned* sp = astamp + (lane & 7);
            unsigned tgt = (unsigned)(t + 1);
            if (lane == 8) sp = xstamp + gc;
            while (__any((int)(ld_stamp(sp) < tgt))) {}
          }
          __builtin_amdgcn_sched_barrier(0);
          const float* xsp = xs + (((size_t)(t & (WSLOT - 1)) * 128 + gc) * 64 + lane) * 16;
          ld_f4(xsp, xv0); ld_f4(xsp + 4, xv1); ld_f4(xsp + 8, xv2); ld_f4(xsp + 12, xv3);
          const bf16* aa = a2buf + (size_t)(t & 1) * (BB * HH) + (size_t)(m0 + lr) * HH + kq;
          bf16x8 fA[8], fB[8];
          #pragma unroll
          for (int j = 0; j < 8; ++j) ld_frag(aa + j * 16, fA[j]);
          #pragma unroll
          for (int j = 0; j < 8; ++j) ld_frag(aa + (8 + j) * 16, fB[j]);
          VWAIT(8);
          #pragma unroll
          for (int j = 0; j < 8; ++j) {
            if (j & 1) acc1 = MFMA32(fA[j], ldsfrag(wlds, lr, j * 16 + kq), acc1);
            else       acc  = MFMA32(fA[j], ldsfrag(wlds, lr, j * 16 + kq), acc);
          }
          #pragma unroll
          for (int j = 0; j < 8; ++j) ld_frag(aa + (16 + j) * 16, fA[j]);
          VWAIT(8);
          #pragma unroll
          for (int j = 0; j < 8; ++j) {
            if (j & 1) acc1 = MFMA32(fB[j], ldsfrag(wlds, lr, (8 + j) * 16 + kq), acc1);
            else       acc  = MFMA32(fB[j], ldsfrag(wlds, lr, (8 + j) * 16 + kq), acc);
          }
          #pragma unroll
          for (int j = 0; j < 8; ++j) ld_frag(aa + (24 + j) * 16, fB[j]);
          VWAIT(8);
          #pragma unroll
          for (int j = 0; j < 8; ++j) {
            if (j & 1) acc1 = MFMA32(fA[j], ldsfrag(wlds, lr, (16 + j) * 16 + kq), acc1);
            else       acc  = MFMA32(fA[j], ldsfrag(wlds, lr, (16 + j) * 16 + kq), acc);
          }
          VWAIT(0);
          #pragma unroll
          for (int j = 0; j < 8; ++j) {
            if (j & 1) acc1 = MFMA32(fB[j], ldsfrag(wlds, lr, (24 + j) * 16 + kq), acc1);
            else       acc  = MFMA32(fB[j], ldsfrag(wlds, lr, (24 + j) * 16 + kq), acc);
          }
        } else {
          {  // t==0: only x(0) needed
            const unsigned* sp = xstamp + gc;
            while (__any((int)(ld_stamp(sp) < 1u))) {}
          }
          __builtin_amdgcn_sched_barrier(0);
          const float* xsp = xs + ((size_t)gc * 64 + lane) * 16;
          ld_f4(xsp, xv0); ld_f4(xsp + 4, xv1); ld_f4(xsp + 8, xv2); ld_f4(xsp + 12, xv3);
          VWAIT(0);
        }
        #pragma unroll
        for (int r = 0; r < 16; ++r) {
          float xadd = (r < 4) ? xv0[r & 3] : (r < 8) ? xv1[r & 3]
                     : (r < 12) ? xv2[r & 3] : xv3[r & 3];
          acc[r] += acc1[r] + xadd;
        }
        __syncthreads();  // MID: zl/z(t) in LDS
        bf16* hd = hbuf + (size_t)(t & 1) * (BB * HH);
        #pragma unroll
        for (int r = 0; r < 16; ++r) {
          int m = mrow + (r & 3) + 8 * (r >> 2);
          float zlv = zlzs[m * 32 + lr];
          float zv = zlzs[2048 + m * 32 + lr];
          float h = zlv * hreg[r] + zv * tanhx(acc[r]);
          hreg[r] = h;
          bf16 hb = (bf16)h;
          st_u16(hd + (size_t)m * HH + n, (unsigned)__builtin_bit_cast(unsigned short, hb));
        }
        asm volatile("s_waitcnt vmcnt(0)" ::: "memory");
      } else {
        f32x16 azl, az;
        #pragma unroll
        for (int r = 0; r < 16; ++r) { azl[r] = 0.0f; az[r] = 0.0f; }
        f32x4 l0, l1, l2, l3, z0, z1, z2, z3;
        if (t > 0) {
          {  // poll h(t-1) + x(t)
            const unsigned* sp = hstamp + (lane & 15);
            unsigned tgt = (unsigned)t;
            if (lane == 16) { sp = xstamp + gzl; tgt = (unsigned)(t + 1); }
            if (lane == 17) { sp = xstamp + gz; tgt = (unsigned)(t + 1); }
            while (__any((int)(ld_stamp(sp) < tgt))) {}
          }
          __builtin_amdgcn_sched_barrier(0);
          const float* xl = xs + (((size_t)(t & (WSLOT - 1)) * 128 + gzl) * 64 + lane) * 16;
          const float* xz = xs + (((size_t)(t & (WSLOT - 1)) * 128 + gz) * 64 + lane) * 16;
          ld_f4(xl, l0); ld_f4(xl + 4, l1); ld_f4(xl + 8, l2); ld_f4(xl + 12, l3);
          ld_f4(xz, z0); ld_f4(xz + 4, z1); ld_f4(xz + 8, z2); ld_f4(xz + 12, z3);
          const bf16* hsA = hbuf + (size_t)((t - 1) & 1) * (BB * HH) + (size_t)(m0 + lr) * HH + kq;
          const bf16* bl = whhzz + (size_t)n * HH + kq;
          const bf16* bz = whhzz + (size_t)(512 + n) * HH + kq;
          bf16x8 A[2][4], Wl[2][4], Wz[2][4];
          #pragma unroll
          for (int j = 0; j < 4; ++j) {
            ld_frag(hsA + j * 16, A[0][j]);
            ld_frag_c(bl + j * 16, Wl[0][j]);
            ld_frag_c(bz + j * 16, Wz[0][j]);
          }
          #pragma unroll
          for (int b = 0; b < 8; ++b) {
            const int s = b & 1, ns = s ^ 1;
            if (b < 7) {
              #pragma unroll
              for (int j = 0; j < 4; ++j) {
                ld_frag(hsA + ((b + 1) * 4 + j) * 16, A[ns][j]);
                ld_frag_c(bl + ((b + 1) * 4 + j) * 16, Wl[ns][j]);
                ld_frag_c(bz + ((b + 1) * 4 + j) * 16, Wz[ns][j]);
              }
              VWAIT(12);
            } else {
              VWAIT(0);
            }
            #pragma unroll
            for (int j = 0; j < 4; ++j) {
              azl = MFMA32(A[s][j], Wl[s][j], azl);
              az = MFMA32(A[s][j], Wz[s][j], az);
            }
          }
        } else {
          {
            const unsigned* sp = xstamp + ((lane & 1) ? gz : gzl);
            while (__any((int)(ld_stamp(sp) < 1u))) {}
          }
          __builtin_amdgcn_sched_barrier(0);
          const float* xl = xs + ((size_t)gzl * 64 + lane) * 16;
          const float* xz = xs + ((size_t)gz * 64 + lane) * 16;
          ld_f4(xl, l0); ld_f4(xl + 4, l1); ld_f4(xl + 8, l2); ld_f4(xl + 12, l3);
          ld_f4(xz, z0); ld_f4(xz + 4, z1); ld_f4(xz + 8, z2); ld_f4(xz + 12, z3);
          VWAIT(0);
        }
        #pragma unroll
        for (int r = 0; r < 16; ++r) {
          int m = mrow + (r & 3) + 8 * (r >> 2);
          float xla = (r < 4) ? l0[r & 3] : (r < 8) ? l1[r & 3]
                    : (r < 12) ? l2[r & 3] : l3[r & 3];
          float xza = (r < 4) ? z0[r & 3] : (r < 8) ? z1[r & 3]
                    : (r < 12) ? z2[r & 3] : z3[r & 3];
          zlzs[m * 32 + lr] = sigm(azl[r] + xla);
          zlzs[2048 + m * 32 + lr] = sigm(az[r] + xza);
        }
        __syncthreads();  // MID
      }
      __syncthreads();  // END: h published (crit) / zlzs consumed next iter
      if (tid == 0) st_stamp(hstamp + cj, (unsigned)(t + 1));
      if (crit) {
        // fp32 outputs AFTER the stamp — off the serial chain (next poll's
        // internal vmcnt(0) re-zeroes FIFO accounting before counted waits)
        #pragma unroll
        for (int r = 0; r < 16; ++r) {
          int m = mrow + (r & 3) + 8 * (r >> 2);
          out[(size_t)m * (LL * HH) + (size_t)t * HH + n] = hreg[r];
        }
      }
    }
  }
}

extern "C" void kernel_launch(void* const* d_in, const int* in_sizes, int n_in,
                              void* d_out, int out_size, void* d_ws, size_t ws_size,
                              hipStream_t stream) {
  (void)in_sizes; (void)n_in; (void)out_size; (void)ws_size;
  const float* x     = (const float*)d_in[0];
  const float* wgih  = (const float*)d_in[2];
  const float* bg    = (const float*)d_in[3];
  const float* wglhh = (const float*)d_in[4];
  const float* wcihf = (const float*)d_in[6];
  const float* bc    = (const float*)d_in[7];
  const float* wclhh = (const float*)d_in[8];
  float* out = (float*)d_out;

  char* ws = (char*)d_ws;
  bf16* xbf     = (bf16*)(ws + OFF_X);
  bf16* wgsel   = (bf16*)(ws + OFF_WGSEL);
  bf16* wcb     = (bf16*)(ws + OFF_WCIH);
  bf16* whhzz   = (bf16*)(ws + OFF_WHHZZ);
  bf16* hbuf    = (bf16*)(ws + OFF_HBUF);
  bf16* a2buf   = (bf16*)(ws + OFF_A2);
  float* xsb    = (float*)(ws + OFF_XS);
  unsigned* ctr = (unsigned*)(ws + OFF_CTR);

  hipMemsetAsync(ctr, 0, 1024, stream);  // stamps reset every replay
  hipMemsetAsync(out + (size_t)BB * LL * HH, 0, (size_t)BB * HH * sizeof(float), stream);

  k_cvt_x<<<dim3(32768), dim3(256), 0, stream>>>(x, xbf);
  k_cvt_w<<<dim3(1536), dim3(256), 0, stream>>>(wgih, wcihf, wglhh, wgsel, wcb, whhzz);
  k_main<<<dim3(NLAUNCH), dim3(256), 0, stream>>>(xbf, wgsel, wcb, whhzz, wglhh, wclhh,
                                                  bg, bc, out, hbuf, a2buf, xsb, ctr);
}